// Round 7
// baseline (430.347 us; speedup 1.0000x reference)
//
#include <hip/hip_runtime.h>
#include <hip/hip_cooperative_groups.h>

namespace cg = cooperative_groups;

#define BB   4
#define SS   1024
#define DD   1024
#define HH   16
#define DHH  64
#define LN_EPS  (1e-3f)
#define NTT  ((size_t)BB * SS * DD)   // 4M elements per tensor

typedef unsigned short u16;
typedef __attribute__((ext_vector_type(8))) short bf16x8;
typedef __attribute__((ext_vector_type(4))) float f32x4;

__device__ __forceinline__ u16 f2bf(float f) {
    union { float f; unsigned int u; } v; v.f = f;
    return (u16)((v.u + 0x7FFFu + ((v.u >> 16) & 1u)) >> 16);
}

// async global->LDS, 16B per lane; lane i lands at lds + i*16 (wave-uniform
// base, no per-lane scatter — swizzle is applied to the SOURCE address).
__device__ __forceinline__ void cp16(void* lds, const void* g) {
    __builtin_amdgcn_global_load_lds(
        (const __attribute__((address_space(1))) unsigned int*)g,
        (__attribute__((address_space(3))) unsigned int*)lds, 16, 0, 0);
}

// ===========================================================================
// Phase device functions (shared by the fused cooperative kernel and the
// standalone fallback kernels). All are virtual-block (vb) indexed.
// ===========================================================================

// ---- prep A: fp32 -> bf16 convert of q/k/v into Abf[3][4096][1024] --------
__device__ __forceinline__ void phase_conv(const float* __restrict__ q,
                                           const float* __restrict__ k,
                                           const float* __restrict__ v,
                                           u16* __restrict__ Abf,
                                           int gtid, int nthr) {
    const int total = (int)(3 * NTT / 8);          // 1,572,864 16B chunks
    for (int i = gtid; i < total; i += nthr) {
        const float* s = (i < 524288) ? q : (i < 1048576) ? k : v;
        const int off = i & 524287;
        const float4 f0 = ((const float4*)s)[off * 2];
        const float4 f1 = ((const float4*)s)[off * 2 + 1];
        union { u16 u[8]; uint4 o; } t;
        t.u[0] = f2bf(f0.x); t.u[1] = f2bf(f0.y);
        t.u[2] = f2bf(f0.z); t.u[3] = f2bf(f0.w);
        t.u[4] = f2bf(f1.x); t.u[5] = f2bf(f1.y);
        t.u[6] = f2bf(f1.z); t.u[7] = f2bf(f1.w);
        ((uint4*)Abf)[i] = t.o;
    }
}

// ---- prep B: W[k][n] fp32 -> Wt[n][k] bf16, one 64x64 tile per vb (<768) --
__device__ __forceinline__ void phase_wtile(u16* __restrict__ smem, int vb,
                                            const float* __restrict__ Wq,
                                            const float* __restrict__ Wk,
                                            const float* __restrict__ Wv,
                                            u16* __restrict__ WtA) {
    float (*Ts)[65] = (float (*)[65])smem;         // 16.6 KB of the 32 KB
    const int tid = threadIdx.x;
    const float* W = (vb < 256) ? Wq : (vb < 512) ? Wk : Wv;
    u16* Wt = WtA + (size_t)(vb >> 8) * DD * DD;
    const int idx = vb & 255;
    const int k0 = (idx >> 4) * 64, n0 = (idx & 15) * 64;
    __syncthreads();
    #pragma unroll
    for (int it = 0; it < 4; ++it) {
        const int i2 = tid + it * 256;
        const int r = i2 >> 4, c4 = (i2 & 15) * 4;
        const float4 vv = *(const float4*)&W[(size_t)(k0 + r) * DD + n0 + c4];
        Ts[r][c4 + 0] = vv.x; Ts[r][c4 + 1] = vv.y;
        Ts[r][c4 + 2] = vv.z; Ts[r][c4 + 3] = vv.w;
    }
    __syncthreads();
    const int n = tid >> 2, kc = (tid & 3) * 16;
    #pragma unroll
    for (int p = 0; p < 8; ++p) {
        const unsigned int lo = f2bf(Ts[kc + p * 2 + 0][n]);
        const unsigned int hi = f2bf(Ts[kc + p * 2 + 1][n]);
        *(unsigned int*)&Wt[(size_t)(n0 + n) * DD + k0 + kc + p * 2] = lo | (hi << 16);
    }
}

// ---- GEMM tile: C = A[4096,1024]bf16 @ Wt[n][k]bf16, tile 128 x (NJ*32) ---
// XOR-swizzled chunk layout: 16B-slot(r,c) = r*8 + (c ^ (r&7)).
template <int NJ>
__device__ __forceinline__ void gemm_tile(u16* __restrict__ smem,
                                          const u16* __restrict__ A,
                                          const u16* __restrict__ B,
                                          int m0, int n0, int z,
                                          u16* __restrict__ Qbf,
                                          u16* __restrict__ Kbf,
                                          u16* __restrict__ Vtb) {
    u16* As = smem;           // 128 x 64 = 8192 u16
    u16* Bs = smem + 8192;    // (NJ*32) x 64
    const int tid  = threadIdx.x;
    const int wave = tid >> 6, lane = tid & 63;
    const int ln = lane & 15, quad = lane >> 4;
    const int mw = (wave & 1) * 64, nw = (wave >> 1) * (NJ * 16);

    f32x4 acc[4][NJ];
    #pragma unroll
    for (int i = 0; i < 4; ++i)
        #pragma unroll
        for (int j = 0; j < NJ; ++j) acc[i][j] = (f32x4){0.f, 0.f, 0.f, 0.f};

    for (int k0 = 0; k0 < DD; k0 += 64) {
        __syncthreads();
        #pragma unroll
        for (int w = 0; w < 4; ++w) {
            const int s = w * 256 + wave * 64 + lane;
            const int r = s >> 3, csrc = (s & 7) ^ (r & 7);
            cp16(&As[(size_t)(w * 256 + wave * 64) * 8],
                 &A[(size_t)(m0 + r) * DD + k0 + csrc * 8]);
        }
        #pragma unroll
        for (int w = 0; w < NJ; ++w) {
            const int s = w * 256 + wave * 64 + lane;
            const int r = s >> 3, csrc = (s & 7) ^ (r & 7);
            cp16(&Bs[(size_t)(w * 256 + wave * 64) * 8],
                 &B[(size_t)(n0 + r) * DD + k0 + csrc * 8]);
        }
        __syncthreads();

        #pragma unroll
        for (int kk = 0; kk < 2; ++kk) {
            bf16x8 af[4], bfv[NJ];
            #pragma unroll
            for (int i = 0; i < 4; ++i) {
                const int r = mw + i * 16 + ln;
                af[i] = *(const bf16x8*)&As[((r << 3) + ((kk * 4 + quad) ^ (r & 7))) << 3];
            }
            #pragma unroll
            for (int j = 0; j < NJ; ++j) {
                const int r = nw + j * 16 + ln;
                bfv[j] = *(const bf16x8*)&Bs[((r << 3) + ((kk * 4 + quad) ^ (r & 7))) << 3];
            }
            #pragma unroll
            for (int i = 0; i < 4; ++i)
                #pragma unroll
                for (int j = 0; j < NJ; ++j)
                    acc[i][j] = __builtin_amdgcn_mfma_f32_16x16x32_bf16(af[i], bfv[j], acc[i][j], 0, 0, 0);
        }
    }

    if (z < 2) {
        u16* C = (z == 0) ? Qbf : Kbf;
        const float scale = (z == 0) ? 0.125f : 1.0f;   // fold 1/sqrt(64) into Q
        #pragma unroll
        for (int i = 0; i < 4; ++i) {
            const int mbase = m0 + mw + i * 16 + quad * 4;
            const int bb = mbase >> 10, sb = mbase & 1023;
            #pragma unroll
            for (int j = 0; j < NJ; ++j) {
                const int n = n0 + nw + j * 16 + ln;
                const int hh = n >> 6, dh = n & 63;
                #pragma unroll
                for (int r = 0; r < 4; ++r)
                    C[(((size_t)bb * HH + hh) * SS + sb + r) * DHH + dh] =
                        f2bf(acc[i][j][r] * scale);
            }
        }
    } else {
        #pragma unroll
        for (int i = 0; i < 4; ++i) {
            const int mbase = m0 + mw + i * 16 + quad * 4;
            const int bb = mbase >> 10, sb = mbase & 1023;
            #pragma unroll
            for (int j = 0; j < NJ; ++j) {
                const int n = n0 + nw + j * 16 + ln;
                const int hh = n >> 6, dh = n & 63;
                uint2 pk;
                pk.x = (unsigned int)f2bf(acc[i][j][0]) | ((unsigned int)f2bf(acc[i][j][1]) << 16);
                pk.y = (unsigned int)f2bf(acc[i][j][2]) | ((unsigned int)f2bf(acc[i][j][3]) << 16);
                *(uint2*)&Vtb[(((size_t)bb * HH + hh) * DHH + dh) * SS + sb] = pk;
            }
        }
    }
}

// ---- GEMM vb dispatch: 1024 tiles (Q 256@128x128, K 256@128x128, V 512@128x64)
__device__ __forceinline__ void phase_gemm(u16* __restrict__ smem, int vb,
                                           const u16* __restrict__ Abf,
                                           const u16* __restrict__ WtA,
                                           u16* __restrict__ Qbf,
                                           u16* __restrict__ Kbf,
                                           u16* __restrict__ Vtb) {
    const int z = (vb < 256) ? 0 : (vb < 512) ? 1 : 2;
    const int xcd = vb & 7;
    const u16* A = Abf + (size_t)z * NTT;
    const u16* B = WtA + (size_t)z * DD * DD;
    if (z < 2) {
        const int t = (vb & 255) >> 3;               // 0..31
        gemm_tile<4>(smem, A, B, (xcd * 4 + (t & 3)) * 128, (t >> 2) * 128,
                     z, Qbf, Kbf, Vtb);
    } else {
        const int t = (vb - 512) >> 3;               // 0..63
        gemm_tile<2>(smem, A, B, (xcd * 4 + (t & 3)) * 128, (t >> 2) * 64,
                     z, Qbf, Kbf, Vtb);
    }
}

// ---- attention vb (0..1023): 64-key tiles, no-max softmax ------------------
__device__ __forceinline__ void phase_attn(u16* __restrict__ smem, int vb,
                                           const u16* __restrict__ Qbf,
                                           const u16* __restrict__ Kbf,
                                           const u16* __restrict__ Vtb,
                                           const int* __restrict__ qmask,
                                           const int* __restrict__ kmask,
                                           float* __restrict__ Ob) {
    u16* QPs = smem;            // 64*68 = 4352 u16 (Q stage, then Ps)
    u16* Ks  = smem + 4352;     // 64*64
    u16* Vs  = smem + 8448;     // 64*64
    const int tid  = threadIdx.x;
    const int wave = tid >> 6, lane = tid & 63;
    const int ln = lane & 15, quad = lane >> 4;
    const int xcd  = vb & 7;
    const int rest = vb >> 3;                // 0..127
    const int bh   = (rest & 7) * 8 + xcd;   // 0..63
    const int qt   = rest >> 3;              // 0..15
    const int b    = bh >> 4, h = bh & 15;
    const int q0   = qt * 64;
    const size_t bhs = (size_t)b * HH + h;

    __syncthreads();   // prior smem use done before restage
    #pragma unroll
    for (int w = 0; w < 2; ++w) {
        const int s = w * 256 + wave * 64 + lane;
        const int r = s >> 3, csrc = (s & 7) ^ (r & 7);
        cp16(&QPs[(size_t)(w * 256 + wave * 64) * 8],
             &Qbf[(bhs * SS + q0 + r) * DHH + csrc * 8]);
    }
    __syncthreads();

    bf16x8 qf[2];
    #pragma unroll
    for (int kk = 0; kk < 2; ++kk) {
        const int r = wave * 16 + ln;
        qf[kk] = *(const bf16x8*)&QPs[((r << 3) + ((kk * 4 + quad) ^ (r & 7))) << 3];
    }

    f32x4 o[4] = {};
    float lsum[4] = {0.f, 0.f, 0.f, 0.f};
    const f32x4 zero = {0.f, 0.f, 0.f, 0.f};

    for (int kt = 0; kt < SS / 64; ++kt) {
        __syncthreads();   // prior tile's reads done before restage
        #pragma unroll
        for (int w = 0; w < 2; ++w) {
            const int s = w * 256 + wave * 64 + lane;
            const int r = s >> 3, csrc = (s & 7) ^ (r & 7);
            cp16(&Ks[(size_t)(w * 256 + wave * 64) * 8],
                 &Kbf[(bhs * SS + kt * 64 + r) * DHH + csrc * 8]);
            cp16(&Vs[(size_t)(w * 256 + wave * 64) * 8],
                 &Vtb[(bhs * DHH + r) * SS + kt * 64 + csrc * 8]);
        }
        __syncthreads();

        // S = Q @ K^T (Q pre-scaled); p = mask * exp(s); spill to Ps
        #pragma unroll
        for (int nt = 0; nt < 4; ++nt) {
            const int krow = nt * 16 + ln;
            const bf16x8 k0f = *(const bf16x8*)&Ks[((krow << 3) + ((0 + quad) ^ (krow & 7))) << 3];
            const bf16x8 k1f = *(const bf16x8*)&Ks[((krow << 3) + ((4 + quad) ^ (krow & 7))) << 3];
            f32x4 sacc = __builtin_amdgcn_mfma_f32_16x16x32_bf16(qf[0], k0f, zero, 0, 0, 0);
            sacc = __builtin_amdgcn_mfma_f32_16x16x32_bf16(qf[1], k1f, sacc, 0, 0, 0);
            const int km = kmask[b * SS + kt * 64 + krow];
            #pragma unroll
            for (int r = 0; r < 4; ++r) {
                const float p = km ? __expf(sacc[r]) : 0.0f;
                lsum[r] += p;
                QPs[(wave * 16 + quad * 4 + r) * 68 + nt * 16 + ln] = f2bf(p);
            }
        }
        // Ps rows are wave-private; same-wave DS ordering covers the RAW.

        // O += P @ V
        #pragma unroll
        for (int kk2 = 0; kk2 < 2; ++kk2) {
            const bf16x8 pf = *(const bf16x8*)&QPs[(wave * 16 + ln) * 68 + kk2 * 32 + quad * 8];
            #pragma unroll
            for (int nt2 = 0; nt2 < 4; ++nt2) {
                const int vrow = nt2 * 16 + ln;
                const bf16x8 vf = *(const bf16x8*)&Vs[((vrow << 3) + ((kk2 * 4 + quad) ^ (vrow & 7))) << 3];
                o[nt2] = __builtin_amdgcn_mfma_f32_16x16x32_bf16(pf, vf, o[nt2], 0, 0, 0);
            }
        }
    }

    // epilogue: one cross-lane l-reduction, normalize, query mask, store
    #pragma unroll
    for (int r = 0; r < 4; ++r) {
        #pragma unroll
        for (int off = 1; off < 16; off <<= 1)
            lsum[r] += __shfl_xor(lsum[r], off);
        const int qq = q0 + wave * 16 + quad * 4 + r;
        const float scale = (float)qmask[b * SS + qq] / lsum[r];
        #pragma unroll
        for (int nt2 = 0; nt2 < 4; ++nt2)
            Ob[((size_t)b * SS + qq) * DD + h * DHH + nt2 * 16 + ln] = o[nt2][r] * scale;
    }
}

// ---- residual + LayerNorm for one (b,s) row -------------------------------
__device__ __forceinline__ void phase_ln(int row, float* __restrict__ sred,
                                         const float* __restrict__ q,
                                         const float* __restrict__ Ob,
                                         const float* __restrict__ gamma,
                                         const float* __restrict__ beta,
                                         float* __restrict__ out) {
    const int tid = threadIdx.x;
    const int wid = tid >> 6, lane = tid & 63;
    const float4 qv = ((const float4*)q)[(size_t)row * 256 + tid];
    const float4 av = ((const float4*)Ob)[(size_t)row * 256 + tid];
    float4 vv;
    vv.x = qv.x + av.x; vv.y = qv.y + av.y;
    vv.z = qv.z + av.z; vv.w = qv.w + av.w;

    float sum = vv.x + vv.y + vv.z + vv.w;
    #pragma unroll
    for (int off = 32; off; off >>= 1) sum += __shfl_down(sum, off);
    if (lane == 0) sred[wid] = sum;
    __syncthreads();
    const float mean = (sred[0] + sred[1] + sred[2] + sred[3]) * (1.0f / DD);
    __syncthreads();

    const float dx = vv.x - mean, dy = vv.y - mean;
    const float dz = vv.z - mean, dw = vv.w - mean;
    float vs = dx * dx + dy * dy + dz * dz + dw * dw;
    #pragma unroll
    for (int off = 32; off; off >>= 1) vs += __shfl_down(vs, off);
    if (lane == 0) sred[wid] = vs;
    __syncthreads();
    const float var = (sred[0] + sred[1] + sred[2] + sred[3]) * (1.0f / DD);
    const float inv = rsqrtf(var + LN_EPS);

    const float4 g  = ((const float4*)gamma)[tid];
    const float4 bt = ((const float4*)beta)[tid];
    float4 ov;
    ov.x = g.x * dx * inv + bt.x; ov.y = g.y * dy * inv + bt.y;
    ov.z = g.z * dz * inv + bt.z; ov.w = g.w * dw * inv + bt.w;
    ((float4*)out)[(size_t)row * 256 + tid] = ov;
    __syncthreads();   // sred reused by caller's next row
}

// ===========================================================================
// Fused cooperative kernel: prep -> gemm -> attn -> ln, grid-size agnostic.
// LDS exactly 32 KB (sred aliases smem) -> 4+ blocks/CU.
// ===========================================================================
__global__ __launch_bounds__(256, 4) void fused_all(
    const float* __restrict__ q, const float* __restrict__ k,
    const float* __restrict__ v, const int* __restrict__ qmask,
    const int* __restrict__ kmask, const float* __restrict__ Wq,
    const float* __restrict__ Wk, const float* __restrict__ Wv,
    const float* __restrict__ gamma, const float* __restrict__ beta,
    float* __restrict__ out, u16* __restrict__ ws) {

    __shared__ __align__(16) u16 smem[16384];   // exactly 32 KB, phase-overlaid
    cg::grid_group grid = cg::this_grid();

    const int bid = blockIdx.x, nb = gridDim.x;
    const int tid = threadIdx.x;

    // workspace layout (54 MB): Abf[3] 24MB (Ob 16MB aliases it; phases are
    // separated by grid.sync) | Qbf 8 | Kbf 8 | Vtb 8 | Wt 6
    u16*   Abf = ws;
    float* Ob  = (float*)ws;
    u16*   Qbf = ws + 3 * NTT;
    u16*   Kbf = Qbf + NTT;
    u16*   Vtb = Kbf + NTT;
    u16*   WtA = Vtb + NTT;

    for (int vb = bid; vb < 768; vb += nb)
        phase_wtile(smem, vb, Wq, Wk, Wv, WtA);
    phase_conv(q, k, v, Abf, bid * 256 + tid, nb * 256);

    grid.sync();

    for (int vb = bid; vb < 1024; vb += nb)
        phase_gemm(smem, vb, Abf, WtA, Qbf, Kbf, Vtb);

    grid.sync();

    for (int vb = bid; vb < 1024; vb += nb)
        phase_attn(smem, vb, Qbf, Kbf, Vtb, qmask, kmask, Ob);

    grid.sync();

    float* sred = (float*)smem;
    for (int row = bid * 4; row < BB * SS; row += nb * 4)
        #pragma unroll
        for (int rr = 0; rr < 4; ++rr)
            phase_ln(row + rr, sred, q, Ob, gamma, beta, out);
}

// ===========================================================================
// Standalone fallback kernels (same phases), used if coop launch is rejected.
// ===========================================================================
__global__ __launch_bounds__(256, 4) void k_prep(
    const float* q, const float* k, const float* v,
    const float* Wq, const float* Wk, const float* Wv,
    u16* Abf, u16* WtA) {
    __shared__ __align__(16) u16 smem[16384];
    if (blockIdx.x < 768) phase_wtile(smem, blockIdx.x, Wq, Wk, Wv, WtA);
    phase_conv(q, k, v, Abf, blockIdx.x * 256 + threadIdx.x, gridDim.x * 256);
}

__global__ __launch_bounds__(256, 4) void k_gemm(
    const u16* Abf, const u16* WtA, u16* Qbf, u16* Kbf, u16* Vtb) {
    __shared__ __align__(16) u16 smem[16384];
    phase_gemm(smem, blockIdx.x, Abf, WtA, Qbf, Kbf, Vtb);
}

__global__ __launch_bounds__(256, 4) void k_attn(
    const u16* Qbf, const u16* Kbf, const u16* Vtb,
    const int* qmask, const int* kmask, float* Ob) {
    __shared__ __align__(16) u16 smem[16384];
    phase_attn(smem, blockIdx.x, Qbf, Kbf, Vtb, qmask, kmask, Ob);
}

__global__ __launch_bounds__(256) void k_ln(
    const float* q, const float* Ob, const float* gamma, const float* beta,
    float* out) {
    __shared__ float sred[4];
    #pragma unroll
    for (int rr = 0; rr < 4; ++rr)
        phase_ln(blockIdx.x * 4 + rr, sred, q, Ob, gamma, beta, out);
}

// ---------------------------------------------------------------------------
extern "C" void kernel_launch(void* const* d_in, const int* in_sizes, int n_in,
                              void* d_out, int out_size, void* d_ws, size_t ws_size,
                              hipStream_t stream) {
    const float* queries = (const float*)d_in[0];
    const float* keys    = (const float*)d_in[1];
    const float* values  = (const float*)d_in[2];
    const int*   qmask   = (const int*)d_in[3];
    const int*   kmask   = (const int*)d_in[4];
    const float* Wq      = (const float*)d_in[5];
    const float* Wk      = (const float*)d_in[6];
    const float* Wv      = (const float*)d_in[7];
    const float* gamma   = (const float*)d_in[8];
    const float* beta    = (const float*)d_in[9];
    float* out = (float*)d_out;
    u16* ws = (u16*)d_ws;

    // Deterministic host-side queries (capture-safe, same result every call).
    int dev = 0;
    (void)hipGetDevice(&dev);
    int nCU = 0;
    (void)hipDeviceGetAttribute(&nCU, hipDeviceAttributeMultiprocessorCount, dev);
    int occ = 0;
    (void)hipOccupancyMaxActiveBlocksPerMultiprocessor(&occ, fused_all, 256, 0);
    long maxb = (long)occ * (long)nCU;

    void* args[] = {
        (void*)&queries, (void*)&keys, (void*)&values,
        (void*)&qmask, (void*)&kmask,
        (void*)&Wq, (void*)&Wk, (void*)&Wv,
        (void*)&gamma, (void*)&beta,
        (void*)&out, (void*)&ws
    };

    bool done = false;
    long g = (maxb < 1024) ? maxb : 1024;
    for (; g >= 256 && !done; g >>= 1) {
        hipError_t e = hipLaunchCooperativeKernel((void*)fused_all,
                                                  dim3((unsigned)g), dim3(256),
                                                  args, 0, stream);
        if (e == hipSuccess) done = true;
        else (void)hipGetLastError();   // clear error state, try smaller grid
    }

    if (!done) {
        // Fallback: identical phases as 4 standalone launches (≈ R5 path).
        u16*   Abf = ws;
        float* Ob  = (float*)ws;
        u16*   Qbf = ws + 3 * NTT;
        u16*   Kbf = Qbf + NTT;
        u16*   Vtb = Kbf + NTT;
        u16*   WtA = Vtb + NTT;
        k_prep<<<1024, 256, 0, stream>>>(queries, keys, values, Wq, Wk, Wv, Abf, WtA);
        k_gemm<<<1024, 256, 0, stream>>>(Abf, WtA, Qbf, Kbf, Vtb);
        k_attn<<<1024, 256, 0, stream>>>(Qbf, Kbf, Vtb, qmask, kmask, Ob);
        k_ln<<<1024, 256, 0, stream>>>(queries, Ob, gamma, beta, out);
    }
}

// Round 8
// 207.411 us; speedup vs baseline: 2.0749x; 2.0749x over previous
//
#include <hip/hip_runtime.h>

#define BB   4
#define SS   1024
#define DD   1024
#define HH   16
#define DHH  64
#define LN_EPS  (1e-3f)
#define NTT  ((size_t)BB * SS * DD)   // 4M elements per tensor

typedef unsigned short u16;
typedef __attribute__((ext_vector_type(8))) short bf16x8;
typedef __attribute__((ext_vector_type(4))) float f32x4;

__device__ __forceinline__ u16 f2bf(float f) {
    union { float f; unsigned int u; } v; v.f = f;
    return (u16)((v.u + 0x7FFFu + ((v.u >> 16) & 1u)) >> 16);
}

// async global->LDS, 16B per lane; lane i lands at lds + i*16 (wave-uniform
// base, no per-lane scatter — swizzle is applied to the SOURCE address).
__device__ __forceinline__ void cp16(void* lds, const void* g) {
    __builtin_amdgcn_global_load_lds(
        (const __attribute__((address_space(1))) unsigned int*)g,
        (__attribute__((address_space(3))) unsigned int*)lds, 16, 0, 0);
}

// ===========================================================================
// Phase device functions (correctness-proven in R7's passing run).
// ===========================================================================

// ---- prep A: fp32 -> bf16 convert of q/k/v into Abf[3][4096][1024] --------
__device__ __forceinline__ void phase_conv(const float* __restrict__ q,
                                           const float* __restrict__ k,
                                           const float* __restrict__ v,
                                           u16* __restrict__ Abf,
                                           int gtid, int nthr) {
    const int total = (int)(3 * NTT / 8);          // 1,572,864 16B chunks
    for (int i = gtid; i < total; i += nthr) {
        const float* s = (i < 524288) ? q : (i < 1048576) ? k : v;
        const int off = i & 524287;
        const float4 f0 = ((const float4*)s)[off * 2];
        const float4 f1 = ((const float4*)s)[off * 2 + 1];
        union { u16 u[8]; uint4 o; } t;
        t.u[0] = f2bf(f0.x); t.u[1] = f2bf(f0.y);
        t.u[2] = f2bf(f0.z); t.u[3] = f2bf(f0.w);
        t.u[4] = f2bf(f1.x); t.u[5] = f2bf(f1.y);
        t.u[6] = f2bf(f1.z); t.u[7] = f2bf(f1.w);
        ((uint4*)Abf)[i] = t.o;
    }
}

// ---- prep B: W[k][n] fp32 -> Wt[n][k] bf16, one 64x64 tile per vb (<768) --
__device__ __forceinline__ void phase_wtile(float (*Ts)[65], int vb,
                                            const float* __restrict__ Wq,
                                            const float* __restrict__ Wk,
                                            const float* __restrict__ Wv,
                                            u16* __restrict__ WtA) {
    const int tid = threadIdx.x;
    const float* W = (vb < 256) ? Wq : (vb < 512) ? Wk : Wv;
    u16* Wt = WtA + (size_t)(vb >> 8) * DD * DD;
    const int idx = vb & 255;
    const int k0 = (idx >> 4) * 64, n0 = (idx & 15) * 64;
    #pragma unroll
    for (int it = 0; it < 4; ++it) {
        const int i2 = tid + it * 256;
        const int r = i2 >> 4, c4 = (i2 & 15) * 4;
        const float4 vv = *(const float4*)&W[(size_t)(k0 + r) * DD + n0 + c4];
        Ts[r][c4 + 0] = vv.x; Ts[r][c4 + 1] = vv.y;
        Ts[r][c4 + 2] = vv.z; Ts[r][c4 + 3] = vv.w;
    }
    __syncthreads();
    const int n = tid >> 2, kc = (tid & 3) * 16;
    #pragma unroll
    for (int p = 0; p < 8; ++p) {
        const unsigned int lo = f2bf(Ts[kc + p * 2 + 0][n]);
        const unsigned int hi = f2bf(Ts[kc + p * 2 + 1][n]);
        *(unsigned int*)&Wt[(size_t)(n0 + n) * DD + k0 + kc + p * 2] = lo | (hi << 16);
    }
}

// ---- GEMM tile: C = A[4096,1024]bf16 @ Wt[n][k]bf16, tile 128 x (NJ*32) ---
// XOR-swizzled chunk layout: 16B-slot(r,c) = r*8 + (c ^ (r&7)).
template <int NJ>
__device__ __forceinline__ void gemm_tile(u16* __restrict__ smem,
                                          const u16* __restrict__ A,
                                          const u16* __restrict__ B,
                                          int m0, int n0, int z,
                                          u16* __restrict__ Qbf,
                                          u16* __restrict__ Kbf,
                                          u16* __restrict__ Vtb) {
    u16* As = smem;           // 128 x 64 = 8192 u16
    u16* Bs = smem + 8192;    // (NJ*32) x 64
    const int tid  = threadIdx.x;
    const int wave = tid >> 6, lane = tid & 63;
    const int ln = lane & 15, quad = lane >> 4;
    const int mw = (wave & 1) * 64, nw = (wave >> 1) * (NJ * 16);

    f32x4 acc[4][NJ];
    #pragma unroll
    for (int i = 0; i < 4; ++i)
        #pragma unroll
        for (int j = 0; j < NJ; ++j) acc[i][j] = (f32x4){0.f, 0.f, 0.f, 0.f};

    for (int k0 = 0; k0 < DD; k0 += 64) {
        __syncthreads();
        #pragma unroll
        for (int w = 0; w < 4; ++w) {
            const int s = w * 256 + wave * 64 + lane;
            const int r = s >> 3, csrc = (s & 7) ^ (r & 7);
            cp16(&As[(size_t)(w * 256 + wave * 64) * 8],
                 &A[(size_t)(m0 + r) * DD + k0 + csrc * 8]);
        }
        #pragma unroll
        for (int w = 0; w < NJ; ++w) {
            const int s = w * 256 + wave * 64 + lane;
            const int r = s >> 3, csrc = (s & 7) ^ (r & 7);
            cp16(&Bs[(size_t)(w * 256 + wave * 64) * 8],
                 &B[(size_t)(n0 + r) * DD + k0 + csrc * 8]);
        }
        __syncthreads();

        #pragma unroll
        for (int kk = 0; kk < 2; ++kk) {
            bf16x8 af[4], bfv[NJ];
            #pragma unroll
            for (int i = 0; i < 4; ++i) {
                const int r = mw + i * 16 + ln;
                af[i] = *(const bf16x8*)&As[((r << 3) + ((kk * 4 + quad) ^ (r & 7))) << 3];
            }
            #pragma unroll
            for (int j = 0; j < NJ; ++j) {
                const int r = nw + j * 16 + ln;
                bfv[j] = *(const bf16x8*)&Bs[((r << 3) + ((kk * 4 + quad) ^ (r & 7))) << 3];
            }
            #pragma unroll
            for (int i = 0; i < 4; ++i)
                #pragma unroll
                for (int j = 0; j < NJ; ++j)
                    acc[i][j] = __builtin_amdgcn_mfma_f32_16x16x32_bf16(af[i], bfv[j], acc[i][j], 0, 0, 0);
        }
    }

    if (z < 2) {
        u16* C = (z == 0) ? Qbf : Kbf;
        const float scale = (z == 0) ? 0.125f : 1.0f;   // fold 1/sqrt(64) into Q
        #pragma unroll
        for (int i = 0; i < 4; ++i) {
            const int mbase = m0 + mw + i * 16 + quad * 4;
            const int bb = mbase >> 10, sb = mbase & 1023;
            #pragma unroll
            for (int j = 0; j < NJ; ++j) {
                const int n = n0 + nw + j * 16 + ln;
                const int hh = n >> 6, dh = n & 63;
                #pragma unroll
                for (int r = 0; r < 4; ++r)
                    C[(((size_t)bb * HH + hh) * SS + sb + r) * DHH + dh] =
                        f2bf(acc[i][j][r] * scale);
            }
        }
    } else {
        #pragma unroll
        for (int i = 0; i < 4; ++i) {
            const int mbase = m0 + mw + i * 16 + quad * 4;
            const int bb = mbase >> 10, sb = mbase & 1023;
            #pragma unroll
            for (int j = 0; j < NJ; ++j) {
                const int n = n0 + nw + j * 16 + ln;
                const int hh = n >> 6, dh = n & 63;
                uint2 pk;
                pk.x = (unsigned int)f2bf(acc[i][j][0]) | ((unsigned int)f2bf(acc[i][j][1]) << 16);
                pk.y = (unsigned int)f2bf(acc[i][j][2]) | ((unsigned int)f2bf(acc[i][j][3]) << 16);
                *(uint2*)&Vtb[(((size_t)bb * HH + hh) * DHH + dh) * SS + sb] = pk;
            }
        }
    }
}

// ---- GEMM vb dispatch: 1024 balanced tiles ---------------------------------
// Q 256 @128x128, K 256 @128x128, V 512 @128x64. xcd = vb&7 owns m-tiles
// 4*xcd..4*xcd+3 -> per-XCD L2 working set (A 1MB + B 2MB) fits 4MB L2.
__device__ __forceinline__ void phase_gemm(u16* __restrict__ smem, int vb,
                                           const u16* __restrict__ Abf,
                                           const u16* __restrict__ WtA,
                                           u16* __restrict__ Qbf,
                                           u16* __restrict__ Kbf,
                                           u16* __restrict__ Vtb) {
    const int z = (vb < 256) ? 0 : (vb < 512) ? 1 : 2;
    const int xcd = vb & 7;
    const u16* A = Abf + (size_t)z * NTT;
    const u16* B = WtA + (size_t)z * DD * DD;
    if (z < 2) {
        const int t = (vb & 255) >> 3;               // 0..31
        gemm_tile<4>(smem, A, B, (xcd * 4 + (t & 3)) * 128, (t >> 2) * 128,
                     z, Qbf, Kbf, Vtb);
    } else {
        const int t = (vb - 512) >> 3;               // 0..63
        gemm_tile<2>(smem, A, B, (xcd * 4 + (t & 3)) * 128, (t >> 2) * 64,
                     z, Qbf, Kbf, Vtb);
    }
}

// ---- attention vb (0..1023): 64-key tiles, no-max softmax ------------------
__device__ __forceinline__ void phase_attn(u16* __restrict__ smem, int vb,
                                           const u16* __restrict__ Qbf,
                                           const u16* __restrict__ Kbf,
                                           const u16* __restrict__ Vtb,
                                           const int* __restrict__ qmask,
                                           const int* __restrict__ kmask,
                                           float* __restrict__ Ob) {
    u16* QPs = smem;            // 64*68 = 4352 u16 (Q stage, then Ps)
    u16* Ks  = smem + 4352;     // 64*64
    u16* Vs  = smem + 8448;     // 64*64
    const int tid  = threadIdx.x;
    const int wave = tid >> 6, lane = tid & 63;
    const int ln = lane & 15, quad = lane >> 4;
    const int xcd  = vb & 7;
    const int rest = vb >> 3;                // 0..127
    const int bh   = (rest & 7) * 8 + xcd;   // 0..63
    const int qt   = rest >> 3;              // 0..15
    const int b    = bh >> 4, h = bh & 15;
    const int q0   = qt * 64;
    const size_t bhs = (size_t)b * HH + h;

    #pragma unroll
    for (int w = 0; w < 2; ++w) {
        const int s = w * 256 + wave * 64 + lane;
        const int r = s >> 3, csrc = (s & 7) ^ (r & 7);
        cp16(&QPs[(size_t)(w * 256 + wave * 64) * 8],
             &Qbf[(bhs * SS + q0 + r) * DHH + csrc * 8]);
    }
    __syncthreads();

    bf16x8 qf[2];
    #pragma unroll
    for (int kk = 0; kk < 2; ++kk) {
        const int r = wave * 16 + ln;
        qf[kk] = *(const bf16x8*)&QPs[((r << 3) + ((kk * 4 + quad) ^ (r & 7))) << 3];
    }

    f32x4 o[4] = {};
    float lsum[4] = {0.f, 0.f, 0.f, 0.f};
    const f32x4 zero = {0.f, 0.f, 0.f, 0.f};

    for (int kt = 0; kt < SS / 64; ++kt) {
        __syncthreads();   // prior tile's reads done before restage
        #pragma unroll
        for (int w = 0; w < 2; ++w) {
            const int s = w * 256 + wave * 64 + lane;
            const int r = s >> 3, csrc = (s & 7) ^ (r & 7);
            cp16(&Ks[(size_t)(w * 256 + wave * 64) * 8],
                 &Kbf[(bhs * SS + kt * 64 + r) * DHH + csrc * 8]);
            cp16(&Vs[(size_t)(w * 256 + wave * 64) * 8],
                 &Vtb[(bhs * DHH + r) * SS + kt * 64 + csrc * 8]);
        }
        __syncthreads();

        // S = Q @ K^T (Q pre-scaled); p = mask * exp(s); spill to Ps
        #pragma unroll
        for (int nt = 0; nt < 4; ++nt) {
            const int krow = nt * 16 + ln;
            const bf16x8 k0f = *(const bf16x8*)&Ks[((krow << 3) + ((0 + quad) ^ (krow & 7))) << 3];
            const bf16x8 k1f = *(const bf16x8*)&Ks[((krow << 3) + ((4 + quad) ^ (krow & 7))) << 3];
            f32x4 sacc = __builtin_amdgcn_mfma_f32_16x16x32_bf16(qf[0], k0f, zero, 0, 0, 0);
            sacc = __builtin_amdgcn_mfma_f32_16x16x32_bf16(qf[1], k1f, sacc, 0, 0, 0);
            const int km = kmask[b * SS + kt * 64 + krow];
            #pragma unroll
            for (int r = 0; r < 4; ++r) {
                const float p = km ? __expf(sacc[r]) : 0.0f;
                lsum[r] += p;
                QPs[(wave * 16 + quad * 4 + r) * 68 + nt * 16 + ln] = f2bf(p);
            }
        }
        // Ps rows are wave-private; same-wave DS ordering covers the RAW.

        // O += P @ V
        #pragma unroll
        for (int kk2 = 0; kk2 < 2; ++kk2) {
            const bf16x8 pf = *(const bf16x8*)&QPs[(wave * 16 + ln) * 68 + kk2 * 32 + quad * 8];
            #pragma unroll
            for (int nt2 = 0; nt2 < 4; ++nt2) {
                const int vrow = nt2 * 16 + ln;
                const bf16x8 vf = *(const bf16x8*)&Vs[((vrow << 3) + ((kk2 * 4 + quad) ^ (vrow & 7))) << 3];
                o[nt2] = __builtin_amdgcn_mfma_f32_16x16x32_bf16(pf, vf, o[nt2], 0, 0, 0);
            }
        }
    }

    // epilogue: one cross-lane l-reduction, normalize, query mask, store
    #pragma unroll
    for (int r = 0; r < 4; ++r) {
        #pragma unroll
        for (int off = 1; off < 16; off <<= 1)
            lsum[r] += __shfl_xor(lsum[r], off);
        const int qq = q0 + wave * 16 + quad * 4 + r;
        const float scale = (float)qmask[b * SS + qq] / lsum[r];
        #pragma unroll
        for (int nt2 = 0; nt2 < 4; ++nt2)
            Ob[((size_t)b * SS + qq) * DD + h * DHH + nt2 * 16 + ln] = o[nt2][r] * scale;
    }
}

// ---- residual + LayerNorm for one (b,s) row -------------------------------
__device__ __forceinline__ void phase_ln(int row, float* __restrict__ sred,
                                         const float* __restrict__ q,
                                         const float* __restrict__ Ob,
                                         const float* __restrict__ gamma,
                                         const float* __restrict__ beta,
                                         float* __restrict__ out) {
    const int tid = threadIdx.x;
    const int wid = tid >> 6, lane = tid & 63;
    const float4 qv = ((const float4*)q)[(size_t)row * 256 + tid];
    const float4 av = ((const float4*)Ob)[(size_t)row * 256 + tid];
    float4 vv;
    vv.x = qv.x + av.x; vv.y = qv.y + av.y;
    vv.z = qv.z + av.z; vv.w = qv.w + av.w;

    float sum = vv.x + vv.y + vv.z + vv.w;
    #pragma unroll
    for (int off = 32; off; off >>= 1) sum += __shfl_down(sum, off);
    if (lane == 0) sred[wid] = sum;
    __syncthreads();
    const float mean = (sred[0] + sred[1] + sred[2] + sred[3]) * (1.0f / DD);
    __syncthreads();

    const float dx = vv.x - mean, dy = vv.y - mean;
    const float dz = vv.z - mean, dw = vv.w - mean;
    float vs = dx * dx + dy * dy + dz * dz + dw * dw;
    #pragma unroll
    for (int off = 32; off; off >>= 1) vs += __shfl_down(vs, off);
    if (lane == 0) sred[wid] = vs;
    __syncthreads();
    const float var = (sred[0] + sred[1] + sred[2] + sred[3]) * (1.0f / DD);
    const float inv = rsqrtf(var + LN_EPS);

    const float4 g  = ((const float4*)gamma)[tid];
    const float4 bt = ((const float4*)beta)[tid];
    float4 ov;
    ov.x = g.x * dx * inv + bt.x; ov.y = g.y * dy * inv + bt.y;
    ov.z = g.z * dz * inv + bt.z; ov.w = g.w * dw * inv + bt.w;
    ((float4*)out)[(size_t)row * 256 + tid] = ov;
    __syncthreads();   // sred reused by caller's next row
}

// ===========================================================================
// Standalone kernels (no cooperative launch — grid.sync measured ~150us/sync
// on gfx950 in R7; 4 plain launches are far cheaper).
// ===========================================================================
__global__ __launch_bounds__(256) void k_prep(
    const float* __restrict__ q, const float* __restrict__ k,
    const float* __restrict__ v,
    const float* __restrict__ Wq, const float* __restrict__ Wk,
    const float* __restrict__ Wv,
    u16* __restrict__ Abf, u16* __restrict__ WtA) {
    __shared__ float Ts[64][65];
    if (blockIdx.x < 768) phase_wtile(Ts, blockIdx.x, Wq, Wk, Wv, WtA);
    phase_conv(q, k, v, Abf, blockIdx.x * 256 + threadIdx.x, gridDim.x * 256);
}

__global__ __launch_bounds__(256, 4) void k_gemm(
    const u16* __restrict__ Abf, const u16* __restrict__ WtA,
    u16* __restrict__ Qbf, u16* __restrict__ Kbf, u16* __restrict__ Vtb) {
    __shared__ __align__(16) u16 smem[16384];   // 32 KB
    phase_gemm(smem, blockIdx.x, Abf, WtA, Qbf, Kbf, Vtb);
}

__global__ __launch_bounds__(256, 4) void k_attn(
    const u16* __restrict__ Qbf, const u16* __restrict__ Kbf,
    const u16* __restrict__ Vtb,
    const int* __restrict__ qmask, const int* __restrict__ kmask,
    float* __restrict__ Ob) {
    __shared__ __align__(16) u16 smem[12544];   // 24.5 KB
    phase_attn(smem, blockIdx.x, Qbf, Kbf, Vtb, qmask, kmask, Ob);
}

__global__ __launch_bounds__(256) void k_ln(
    const float* __restrict__ q, const float* __restrict__ Ob,
    const float* __restrict__ gamma, const float* __restrict__ beta,
    float* __restrict__ out) {
    __shared__ float sred[4];
    #pragma unroll
    for (int rr = 0; rr < 4; ++rr)
        phase_ln(blockIdx.x * 4 + rr, sred, q, Ob, gamma, beta, out);
}

// ---------------------------------------------------------------------------
extern "C" void kernel_launch(void* const* d_in, const int* in_sizes, int n_in,
                              void* d_out, int out_size, void* d_ws, size_t ws_size,
                              hipStream_t stream) {
    const float* queries = (const float*)d_in[0];
    const float* keys    = (const float*)d_in[1];
    const float* values  = (const float*)d_in[2];
    const int*   qmask   = (const int*)d_in[3];
    const int*   kmask   = (const int*)d_in[4];
    const float* Wq      = (const float*)d_in[5];
    const float* Wk      = (const float*)d_in[6];
    const float* Wv      = (const float*)d_in[7];
    const float* gamma   = (const float*)d_in[8];
    const float* beta    = (const float*)d_in[9];
    float* out = (float*)d_out;
    u16* ws = (u16*)d_ws;

    // workspace layout (54 MB): Abf[3] 24MB (Ob 16MB aliases it — stream-
    // ordered: gemm finishes reading Abf before attn writes Ob) | Qbf 8 |
    // Kbf 8 | Vtb 8 | Wt 6
    u16*   Abf = ws;
    float* Ob  = (float*)ws;
    u16*   Qbf = ws + 3 * NTT;
    u16*   Kbf = Qbf + NTT;
    u16*   Vtb = Kbf + NTT;
    u16*   WtA = Vtb + NTT;

    k_prep<<<1024, 256, 0, stream>>>(queries, keys, values, Wq, Wk, Wv, Abf, WtA);
    k_gemm<<<1024, 256, 0, stream>>>(Abf, WtA, Qbf, Kbf, Vtb);
    k_attn<<<1024, 256, 0, stream>>>(Qbf, Kbf, Vtb, qmask, kmask, Ob);
    k_ln<<<1024, 256, 0, stream>>>(queries, Ob, gamma, beta, out);
}